// Round 16
// baseline (44.871 us; speedup 1.0000x reference)
//
#include <hip/hip_runtime.h>
#include <math.h>

#define BDIM 256
#define TP   32                 // output pixels per block (along W)
#define C_   64
#define O_   64
#define H_   128
#define W_   128
#define KK_  9
#define CKK  576
#define HW_  (H_ * W_)          // 16384
#define XTP  72                 // compact x-tile row pad (shorts)
#define XCOLS 34                // compact tile cols (TP + 2 halo)
#define NE   (TP * KK_)         // 288 gather entries
#define NBLK 2048
#define SROW 584                // samp pixel stride in shorts (1168 B; kk stride 64)

// ---- ws layout ----
#define XHBF_OFF  131072
#define WS_NEED   (XHBF_OFF + (size_t)4 * HW_ * C_ * 2)   // ~8.5 MB

typedef short short8 __attribute__((ext_vector_type(8)));
typedef float f32x4  __attribute__((ext_vector_type(4)));

__device__ __forceinline__ unsigned short f2bf(float f) {
    unsigned int u = __float_as_uint(f);
    u += 0x7FFFu + ((u >> 16) & 1u);          // RNE (inputs finite)
    return (unsigned short)(u >> 16);
}

// packed RNE: lo -> bits[15:0], hi -> bits[31:16]
__device__ __forceinline__ unsigned int pk2bf(float lo, float hi) {
    unsigned int r;
    asm("v_cvt_pk_bf16_f32 %0, %1, %2" : "=v"(r) : "v"(lo), "v"(hi));
    return r;
}

__device__ __forceinline__ float bf_lo(unsigned int u) { return __uint_as_float(u << 16); }
__device__ __forceinline__ float bf_hi(unsigned int u) { return __uint_as_float(u & 0xFFFF0000u); }

// ---------------- pre: {x NCHW -> HWC bf16 transpose} + {weight pack} (R15 verbatim) ----
__global__ __launch_bounds__(BDIM) void dcn_pre(
    const float* __restrict__ x,
    unsigned short* __restrict__ xhbf,
    const float* __restrict__ w_off, const float* __restrict__ w_mod,
    const float* __restrict__ w_reg, unsigned short* __restrict__ wpack)
{
    __shared__ float tile[32][33];
    if (blockIdx.x >= 4096) {
        // ---- weight pack (216 blocks * 256 = 55296 threads)
        int i = (blockIdx.x - 4096) * BDIM + threadIdx.x;
        bool isB = i < 36864;
        int r = isB ? i : i - 36864;
        int j    = r & 7;
        int lane = (r >> 3) & 63;
        int t2   = r >> 9;
        int kstep = t2 % 18;
        int tilei = t2 / 18;
        int k  = kstep * 32 + (lane >> 4) * 8 + j;
        int c  = k & 63;
        int kk = k >> 6;
        int col = tilei * 16 + (lane & 15);
        float v;
        if (isB) {
            v = w_reg[(size_t)col * CKK + c * KK_ + kk];
        } else {
            if (col < 18)      v = w_off[(size_t)col * CKK + c * KK_ + kk];
            else if (col < 27) v = w_mod[(size_t)(col - 18) * CKK + c * KK_ + kk];
            else               v = 0.f;
        }
        wpack[i] = f2bf(v);
        return;
    }
    // ---- transpose one (b, y, 32w, 32c) tile -> bf16 HWC
    int wq = blockIdx.x & 3;           // W/32
    int cq = (blockIdx.x >> 2) & 1;    // C/32
    int by = blockIdx.x >> 3;          // b*H + y
    int b = by >> 7, y = by & 127;
    int w0 = wq * 32, c0 = cq * 32;
    int tw = threadIdx.x & 31, tc = threadIdx.x >> 5;
    const float* xp = x + (size_t)b * C_ * HW_ + (size_t)y * W_;
    #pragma unroll
    for (int k = 0; k < 4; ++k)
        tile[tc + k * 8][tw] = xp[(size_t)(c0 + tc + k * 8) * HW_ + w0 + tw];
    __syncthreads();
    // bf16 store: u in [0,512) covers ALL (wp 0..31) x (cp 0..15) -> full 32w x 32c
    unsigned int* opb = (unsigned int*)xhbf + ((size_t)b * HW_ + (size_t)y * W_) * 32;
    for (int u = threadIdx.x; u < 512; u += BDIM) {
        int wp = u >> 4;          // 0..31
        int cp = u & 15;          // 0..15 (channel pair within 32-ch slab)
        opb[(size_t)(w0 + wp) * 32 + (c0 >> 1) + cp] =
            pk2bf(tile[2 * cp][wp], tile[2 * cp + 1][wp]);
    }
}

// ------- main: A(copy) + B(offs/msk MFMA) + C(fold->LDS tabs) + D(gather) + E(MFMA) -------
__global__ __launch_bounds__(BDIM, 3) void dcn_main(
    const unsigned short* __restrict__ xhbf,
    const float* __restrict__ b_off,
    const float* __restrict__ b_mod,
    const unsigned short* __restrict__ wB,
    const unsigned short* __restrict__ wO,
    float* __restrict__ out)
{
    // samp_s hosts: xtile (102*72=7344 shorts) during A-B; offs/msk (floats at
    // short-offset 8192..9920, beyond xtile) during B-C; samples during D-E.
    __shared__ __align__(16) unsigned short samp_s[TP * SROW];  // 37376 B
    __shared__ __align__(16) float4 wtab[NE];                   // 4608 B
    __shared__ ushort4        itab[NE];                         // 2304 B

    float* offs = (float*)(samp_s + 8192);   // 576 floats
    float* msk  = offs + TP * 18;            // 288 floats

    const int t    = threadIdx.x;
    const int wave = t >> 6;
    const int lane = t & 63;
    const int blk  = ((blockIdx.x & 7) << 8) | (blockIdx.x >> 3);   // XCD swizzle
    const int wo0  = (blk & 3) * TP;
    const int ho   = (blk >> 2) & 127;
    const int b    = blk >> 9;

    const unsigned short* xbh = xhbf + (size_t)b * HW_ * C_;

    // ---- A: copy bf16 tile xtile[row=ry*34+col][c] (8 ch per uint4 item)
    for (int u = t; u < 102 * 8; u += BDIM) {
        int row = u >> 3;
        int c8  = (u & 7) * 8;
        int ry  = row / XCOLS;
        int col = row - ry * XCOLS;
        int gy  = ho - 1 + ry;
        int gx  = wo0 - 1 + col;
        uint4 v = make_uint4(0u, 0u, 0u, 0u);
        if (gy >= 0 && gy < H_ && gx >= 0 && gx < W_)
            v = *(const uint4*)&xbh[((size_t)(gy * W_ + gx) << 6) + c8];
        *(uint4*)&samp_s[row * XTP + c8] = v;
    }
    __syncthreads();

    // ---- B: offset(18)+mask(9) conv via MFMA; 1 bp load feeds 2 pixel halves
    if (wave < 2) {
        f32x4 acc0 = {0.f, 0.f, 0.f, 0.f};
        f32x4 acc1 = {0.f, 0.f, 0.f, 0.f};
        const unsigned short* bp = wO + ((size_t)(wave * 18) * 64 + lane) * 8;
        const unsigned short* ap = samp_s + (lane & 15) * XTP + (lane >> 4) * 8;
        #pragma unroll
        for (int ks = 0; ks < 18; ++ks) {
            const int kk = ks >> 1, ky = kk / 3, kx = kk - ky * 3;
            const int ro = (ky * XCOLS + kx) * XTP + (ks & 1) * 32;
            short8 av0 = *(const short8*)&ap[ro];
            short8 av1 = *(const short8*)&ap[ro + 16 * XTP];
            short8 bv  = *(const short8*)bp;  bp += 512;
            acc0 = __builtin_amdgcn_mfma_f32_16x16x32_bf16(av0, bv, acc0, 0, 0, 0);
            acc1 = __builtin_amdgcn_mfma_f32_16x16x32_bf16(av1, bv, acc1, 0, 0, 0);
        }
        int oc   = wave * 16 + (lane & 15);
        int prow = (lane >> 4) * 4;
        if (oc < 18) {
            float bias = b_off[oc];
            #pragma unroll
            for (int r = 0; r < 4; ++r) {
                offs[(prow + r) * 18 + oc]      = acc0[r] + bias;
                offs[(prow + 16 + r) * 18 + oc] = acc1[r] + bias;
            }
        } else if (oc < 27) {
            int mc = oc - 18;
            float bias = b_mod[mc];
            #pragma unroll
            for (int r = 0; r < 4; ++r) {
                msk[(prow + r) * KK_ + mc]      = 2.f / (1.f + expf(-(acc0[r] + bias)));
                msk[(prow + 16 + r) * KK_ + mc] = 2.f / (1.f + expf(-(acc1[r] + bias)));
            }
        }
    }
    __syncthreads();

    // ---- C: positions -> folded (valid x mask x bilinear) weights + clamped idx (LDS)
    for (int e = t; e < NE; e += BDIM) {
        int p  = e / 9;
        int kk = e - p * 9;
        int ky = kk / 3, kx = kk - ky * 3;
        float dy = offs[p * 18 + 2 * kk];
        float dx = offs[p * 18 + 2 * kk + 1];
        float py = dy + (float)(ho - 1 + ky);
        float px = dx + (float)(wo0 + p - 1 + kx);
        float y0f = floorf(py), x0f = floorf(px);
        float wy = py - y0f,    wx = px - x0f;
        int y0 = (int)y0f, x0 = (int)x0f;
        int y1 = y0 + 1,   x1 = x0 + 1;
        float m = msk[p * KK_ + kk];
        float vy0 = (y0 >= 0 && y0 < H_) ? 1.f : 0.f;
        float vy1 = (y1 >= 0 && y1 < H_) ? 1.f : 0.f;
        float vx0 = (x0 >= 0 && x0 < W_) ? 1.f : 0.f;
        float vx1 = (x1 >= 0 && x1 < W_) ? 1.f : 0.f;
        float4 wt;
        wt.x = (1.f - wy) * (1.f - wx) * m * vy0 * vx0;
        wt.y = (1.f - wy) * wx * m * vy0 * vx1;
        wt.z = wy * (1.f - wx) * m * vy1 * vx0;
        wt.w = wy * wx * m * vy1 * vx1;
        int yc0 = min(max(y0, 0), H_ - 1), yc1 = min(max(y1, 0), H_ - 1);
        int xc0 = min(max(x0, 0), W_ - 1), xc1 = min(max(x1, 0), W_ - 1);
        wtab[e] = wt;
        itab[e] = make_ushort4((unsigned short)(yc0 * W_ + xc0),
                               (unsigned short)(yc0 * W_ + xc1),
                               (unsigned short)(yc1 * W_ + xc0),
                               (unsigned short)(yc1 * W_ + xc1));
    }
    __syncthreads();

    // ---- D: bilinear gather from bf16 HWC, 8 ch/lane; tabs preloaded LDS->regs
    {
        const int c8 = (lane & 7) * 8;
        const int q  = lane >> 3;                 // 0..7 (8-lane groups share an entry)
        const int e0 = wave * 72 + q;
        const unsigned short* base = xbh + c8;

        ushort4 ixr[9];
        float4  wtr[9];
        #pragma unroll
        for (int it = 0; it < 9; ++it) {
            ixr[it] = itab[e0 + it * 8];
            wtr[it] = wtab[e0 + it * 8];
        }

        #pragma unroll
        for (int it = 0; it < 9; ++it) {
            const int e  = e0 + it * 8;
            const int p  = (e * 29128) >> 18;     // e/9 for e<288
            const int kk = e - p * 9;
            const int dst = p * SROW + kk * 64;
            float4  wt = wtr[it];
            ushort4 ix = ixr[it];
            uint4 u00 = *(const uint4*)(base + ((size_t)ix.x << 6));
            uint4 u01 = *(const uint4*)(base + ((size_t)ix.y << 6));
            uint4 u10 = *(const uint4*)(base + ((size_t)ix.z << 6));
            uint4 u11 = *(const uint4*)(base + ((size_t)ix.w << 6));
            const unsigned int a00[4] = {u00.x, u00.y, u00.z, u00.w};
            const unsigned int a01[4] = {u01.x, u01.y, u01.z, u01.w};
            const unsigned int a10[4] = {u10.x, u10.y, u10.z, u10.w};
            const unsigned int a11[4] = {u11.x, u11.y, u11.z, u11.w};
            unsigned int pk[4];
            #pragma unroll
            for (int wd = 0; wd < 4; ++wd) {
                float slo = bf_lo(a00[wd]) * wt.x;
                slo = fmaf(bf_lo(a01[wd]), wt.y, slo);
                slo = fmaf(bf_lo(a10[wd]), wt.z, slo);
                slo = fmaf(bf_lo(a11[wd]), wt.w, slo);
                float shi = bf_hi(a00[wd]) * wt.x;
                shi = fmaf(bf_hi(a01[wd]), wt.y, shi);
                shi = fmaf(bf_hi(a10[wd]), wt.z, shi);
                shi = fmaf(bf_hi(a11[wd]), wt.w, shi);
                pk[wd] = pk2bf(slo, shi);
            }
            *(uint4*)&samp_s[dst + c8] = make_uint4(pk[0], pk[1], pk[2], pk[3]);
        }
    }
    __syncthreads();

    // ---- E: out[p][o] via MFMA; 1 bp load feeds 2 pixel halves
    {
        f32x4 acc0 = {0.f, 0.f, 0.f, 0.f};
        f32x4 acc1 = {0.f, 0.f, 0.f, 0.f};
        const unsigned short* bp = wB + ((size_t)(wave * 18) * 64 + lane) * 8;
        const int arow = (lane & 15) * SROW + (lane >> 4) * 8;
        #pragma unroll
        for (int ks = 0; ks < 18; ++ks) {
            const int ro = arow + (ks >> 1) * 64 + (ks & 1) * 32;
            short8 av0 = *(const short8*)&samp_s[ro];
            short8 av1 = *(const short8*)&samp_s[ro + 16 * SROW];
            short8 bv  = *(const short8*)bp;  bp += 512;
            acc0 = __builtin_amdgcn_mfma_f32_16x16x32_bf16(av0, bv, acc0, 0, 0, 0);
            acc1 = __builtin_amdgcn_mfma_f32_16x16x32_bf16(av1, bv, acc1, 0, 0, 0);
        }
        int o    = wave * 16 + (lane & 15);
        int prow = (lane >> 4) * 4;
        float* ob = out + (size_t)b * O_ * HW_ + (size_t)o * HW_ + ho * W_ + wo0;
        #pragma unroll
        for (int r = 0; r < 4; ++r) {
            ob[prow + r]      = acc0[r];
            ob[16 + prow + r] = acc1[r];
        }
    }
}

extern "C" void kernel_launch(void* const* d_in, const int* in_sizes, int n_in,
                              void* d_out, int out_size, void* d_ws, size_t ws_size,
                              hipStream_t stream) {
    const float* x     = (const float*)d_in[0];
    const float* w_off = (const float*)d_in[1];
    const float* b_off = (const float*)d_in[2];
    const float* w_mod = (const float*)d_in[3];
    const float* b_mod = (const float*)d_in[4];
    const float* w_reg = (const float*)d_in[5];
    float* out = (float*)d_out;

    unsigned short* wpack = (unsigned short*)d_ws;
    unsigned short* x_hbf = (unsigned short*)((char*)d_ws + XHBF_OFF);

    dcn_pre<<<4096 + 216, BDIM, 0, stream>>>(x, x_hbf, w_off, w_mod, w_reg, wpack);
    dcn_main<<<NBLK, BDIM, 0, stream>>>(x_hbf, b_off, b_mod,
                                        wpack, wpack + 36864, out);
}

// Round 17
// 42.834 us; speedup vs baseline: 1.0476x; 1.0476x over previous
//
#include <hip/hip_runtime.h>
#include <math.h>

#define BDIM 256
#define TP   32                 // output pixels per block (along W)
#define C_   64
#define O_   64
#define H_   128
#define W_   128
#define KK_  9
#define CKK  576
#define HW_  (H_ * W_)          // 16384
#define KKS  72                 // padded kk-block stride in shorts (144 B)
#define ROWS (KK_ * KKS)        // 648 shorts per pixel row (1296 B)
#define XTP  72                 // compact x-tile row pad (shorts)
#define XCOLS 34                // compact tile cols (TP + 2 halo)
#define NE   (TP * KK_)         // 288 gather entries
#define NBLK 2048

// ---- ws layout (split bf16 path) ----
#define WTAB_OFF  131072
#define ITAB_OFF  (WTAB_OFF + (size_t)NBLK * NE * 16)     //  9,568,256
#define XHBF_OFF  (ITAB_OFF + (size_t)NBLK * NE * 8)      // 14,286,848
#define WS_NEED   (XHBF_OFF + (size_t)4 * HW_ * C_ * 2)   // 22,675,456
// ---- fallback monolithic path ----
#define XHWC_OFF  131072

typedef short short8 __attribute__((ext_vector_type(8)));
typedef float f32x4  __attribute__((ext_vector_type(4)));

__device__ __forceinline__ unsigned short f2bf(float f) {
    unsigned int u = __float_as_uint(f);
    u += 0x7FFFu + ((u >> 16) & 1u);          // RNE (inputs finite)
    return (unsigned short)(u >> 16);
}

// packed RNE: lo -> bits[15:0], hi -> bits[31:16]
__device__ __forceinline__ unsigned int pk2bf(float lo, float hi) {
    unsigned int r;
    asm("v_cvt_pk_bf16_f32 %0, %1, %2" : "=v"(r) : "v"(lo), "v"(hi));
    return r;
}

__device__ __forceinline__ float bf_lo(unsigned int u) { return __uint_as_float(u << 16); }
__device__ __forceinline__ float bf_hi(unsigned int u) { return __uint_as_float(u & 0xFFFF0000u); }

// ---------------- pre: {x NCHW -> HWC transpose (bf16 or fp32)} + {weight pack} ----
// mode 0: write bf16 x_hbf only (split path). mode 1: write fp32 x_hwc only (fallback).
__global__ __launch_bounds__(BDIM) void dcn_pre(
    const float* __restrict__ x, float* __restrict__ xh,
    unsigned short* __restrict__ xhbf, int mode,
    const float* __restrict__ w_off, const float* __restrict__ w_mod,
    const float* __restrict__ w_reg, unsigned short* __restrict__ wpack)
{
    __shared__ float tile[32][33];
    if (blockIdx.x >= 4096) {
        // ---- weight pack (216 blocks * 256 = 55296 threads)
        int i = (blockIdx.x - 4096) * BDIM + threadIdx.x;
        bool isB = i < 36864;
        int r = isB ? i : i - 36864;
        int j    = r & 7;
        int lane = (r >> 3) & 63;
        int t2   = r >> 9;
        int kstep = t2 % 18;
        int tilei = t2 / 18;
        int k  = kstep * 32 + (lane >> 4) * 8 + j;
        int c  = k & 63;
        int kk = k >> 6;
        int col = tilei * 16 + (lane & 15);
        float v;
        if (isB) {
            v = w_reg[(size_t)col * CKK + c * KK_ + kk];
        } else {
            if (col < 18)      v = w_off[(size_t)col * CKK + c * KK_ + kk];
            else if (col < 27) v = w_mod[(size_t)(col - 18) * CKK + c * KK_ + kk];
            else               v = 0.f;
        }
        wpack[i] = f2bf(v);
        return;
    }
    // ---- transpose one (b, y, 32w, 32c) tile
    int wq = blockIdx.x & 3;           // W/32
    int cq = (blockIdx.x >> 2) & 1;    // C/32
    int by = blockIdx.x >> 3;          // b*H + y
    int b = by >> 7, y = by & 127;
    int w0 = wq * 32, c0 = cq * 32;
    int tw = threadIdx.x & 31, tc = threadIdx.x >> 5;
    const float* xp = x + (size_t)b * C_ * HW_ + (size_t)y * W_;
    #pragma unroll
    for (int k = 0; k < 4; ++k)
        tile[tc + k * 8][tw] = xp[(size_t)(c0 + tc + k * 8) * HW_ + w0 + tw];
    __syncthreads();
    if (mode == 0) {
        // bf16 store: u in [0,512) covers ALL (wp 0..31) x (cp 0..15) -> full 32w x 32c
        unsigned int* opb = (unsigned int*)xhbf + ((size_t)b * HW_ + (size_t)y * W_) * 32;
        for (int u = threadIdx.x; u < 512; u += BDIM) {
            int wp = u >> 4;          // 0..31
            int cp = u & 15;          // 0..15 (channel pair within 32-ch slab)
            opb[(size_t)(w0 + wp) * 32 + (c0 >> 1) + cp] =
                pk2bf(tile[2 * cp][wp], tile[2 * cp + 1][wp]);
        }
    } else {
        float* op = xh + ((size_t)b * HW_ + (size_t)y * W_) * C_;
        #pragma unroll
        for (int k = 0; k < 4; ++k)
            op[(size_t)(w0 + tc + k * 8) * C_ + c0 + tw] = tile[tw][tc + k * 8];
    }
}

// ------- kernel 1: tabs = A + B + C (reads bf16 x_hbf; A is a pure copy) -------
__global__ __launch_bounds__(BDIM, 4) void dcn_tabs(
    const unsigned short* __restrict__ xhbf,
    const float* __restrict__ b_off,
    const float* __restrict__ b_mod,
    const unsigned short* __restrict__ wO,
    float4* __restrict__ wtab_g,
    ushort4* __restrict__ itab_g)
{
    __shared__ __align__(16) unsigned short xtile[102 * XTP];   // 14688 B
    __shared__ float offs[TP * 18];                             // 2304 B
    __shared__ float msk [TP * KK_];                            // 1152 B

    const int t    = threadIdx.x;
    const int wave = t >> 6;
    const int lane = t & 63;
    const int blk  = ((blockIdx.x & 7) << 8) | (blockIdx.x >> 3);   // XCD swizzle
    const int wo0  = (blk & 3) * TP;
    const int ho   = (blk >> 2) & 127;
    const int b    = blk >> 9;

    const unsigned short* xbh = xhbf + (size_t)b * HW_ * C_;

    // ---- A: copy bf16 tile (8 ch per uint4 item)
    for (int u = t; u < 102 * 8; u += BDIM) {
        int row = u >> 3;
        int c8  = (u & 7) * 8;
        int ry  = row / XCOLS;
        int col = row - ry * XCOLS;
        int gy  = ho - 1 + ry;
        int gx  = wo0 - 1 + col;
        uint4 v = make_uint4(0u, 0u, 0u, 0u);
        if (gy >= 0 && gy < H_ && gx >= 0 && gx < W_)
            v = *(const uint4*)&xbh[((size_t)(gy * W_ + gx) << 6) + c8];
        *(uint4*)&xtile[row * XTP + c8] = v;
    }
    __syncthreads();

    // ---- B: offset(18)+mask(9) conv via MFMA; 1 bp load feeds 2 pixel halves
    if (wave < 2) {
        f32x4 acc0 = {0.f, 0.f, 0.f, 0.f};
        f32x4 acc1 = {0.f, 0.f, 0.f, 0.f};
        const unsigned short* bp = wO + ((size_t)(wave * 18) * 64 + lane) * 8;
        const unsigned short* ap = xtile + (lane & 15) * XTP + (lane >> 4) * 8;
        #pragma unroll
        for (int ks = 0; ks < 18; ++ks) {
            const int kk = ks >> 1, ky = kk / 3, kx = kk - ky * 3;
            const int ro = (ky * XCOLS + kx) * XTP + (ks & 1) * 32;
            short8 av0 = *(const short8*)&ap[ro];
            short8 av1 = *(const short8*)&ap[ro + 16 * XTP];
            short8 bv  = *(const short8*)bp;  bp += 512;
            acc0 = __builtin_amdgcn_mfma_f32_16x16x32_bf16(av0, bv, acc0, 0, 0, 0);
            acc1 = __builtin_amdgcn_mfma_f32_16x16x32_bf16(av1, bv, acc1, 0, 0, 0);
        }
        int oc   = wave * 16 + (lane & 15);
        int prow = (lane >> 4) * 4;
        if (oc < 18) {
            float bias = b_off[oc];
            #pragma unroll
            for (int r = 0; r < 4; ++r) {
                offs[(prow + r) * 18 + oc]      = acc0[r] + bias;
                offs[(prow + 16 + r) * 18 + oc] = acc1[r] + bias;
            }
        } else if (oc < 27) {
            int mc = oc - 18;
            float bias = b_mod[mc];
            #pragma unroll
            for (int r = 0; r < 4; ++r) {
                msk[(prow + r) * KK_ + mc]      = 2.f / (1.f + expf(-(acc0[r] + bias)));
                msk[(prow + 16 + r) * KK_ + mc] = 2.f / (1.f + expf(-(acc1[r] + bias)));
            }
        }
    }
    __syncthreads();

    // ---- C -> global tabs
    float4*  wg = wtab_g + (size_t)blk * NE;
    ushort4* ig = itab_g + (size_t)blk * NE;
    for (int e = t; e < NE; e += BDIM) {
        int p  = e / 9;
        int kk = e - p * 9;
        int ky = kk / 3, kx = kk - ky * 3;
        float dy = offs[p * 18 + 2 * kk];
        float dx = offs[p * 18 + 2 * kk + 1];
        float py = dy + (float)(ho - 1 + ky);
        float px = dx + (float)(wo0 + p - 1 + kx);
        float y0f = floorf(py), x0f = floorf(px);
        float wy = py - y0f,    wx = px - x0f;
        int y0 = (int)y0f, x0 = (int)x0f;
        int y1 = y0 + 1,   x1 = x0 + 1;
        float m = msk[p * KK_ + kk];
        float vy0 = (y0 >= 0 && y0 < H_) ? 1.f : 0.f;
        float vy1 = (y1 >= 0 && y1 < H_) ? 1.f : 0.f;
        float vx0 = (x0 >= 0 && x0 < W_) ? 1.f : 0.f;
        float vx1 = (x1 >= 0 && x1 < W_) ? 1.f : 0.f;
        float4 wt;
        wt.x = (1.f - wy) * (1.f - wx) * m * vy0 * vx0;
        wt.y = (1.f - wy) * wx * m * vy0 * vx1;
        wt.z = wy * (1.f - wx) * m * vy1 * vx0;
        wt.w = wy * wx * m * vy1 * vx1;
        int yc0 = min(max(y0, 0), H_ - 1), yc1 = min(max(y1, 0), H_ - 1);
        int xc0 = min(max(x0, 0), W_ - 1), xc1 = min(max(x1, 0), W_ - 1);
        wg[e] = wt;
        ig[e] = make_ushort4((unsigned short)(yc0 * W_ + xc0),
                             (unsigned short)(yc0 * W_ + xc1),
                             (unsigned short)(yc1 * W_ + xc0),
                             (unsigned short)(yc1 * W_ + xc1));
    }
}

// ---------------- kernel 2: gather(D, bf16 corners 8ch/lane) + PV(E) ----------------
__global__ __launch_bounds__(BDIM, 3) void dcn_gather(
    const unsigned short* __restrict__ xhbf,
    const float4* __restrict__ wtab_g,
    const ushort4* __restrict__ itab_g,
    const unsigned short* __restrict__ wB,
    float* __restrict__ out)
{
    __shared__ __align__(16) unsigned short samp_s[TP * ROWS];  // 41472 B
    __shared__ __align__(16) float4 wtab[NE];                   // 4608 B
    __shared__ ushort4        itab[NE];                         // 2304 B
    __shared__ unsigned short dsttab[NE];                       // 576 B

    const int t    = threadIdx.x;
    const int wave = t >> 6;
    const int lane = t & 63;
    const int blk  = ((blockIdx.x & 7) << 8) | (blockIdx.x >> 3);   // same swizzle
    const int wo0  = (blk & 3) * TP;
    const int ho   = (blk >> 2) & 127;
    const int b    = blk >> 9;

    const unsigned short* xbh = xhbf + (size_t)b * HW_ * C_;

    // ---- stage tabs global -> LDS (coalesced)
    {
        const float4*  wg = wtab_g + (size_t)blk * NE;
        const ushort4* ig = itab_g + (size_t)blk * NE;
        for (int e = t; e < NE; e += BDIM) {
            wtab[e]   = wg[e];
            itab[e]   = ig[e];
            int p = e / 9, kk = e - p * 9;
            dsttab[e] = (unsigned short)(p * ROWS + kk * KKS);
        }
    }
    __syncthreads();

    // ---- D: bilinear gather from bf16 HWC, 8 ch/lane (8 lanes per entry)
    {
        const int c8 = (lane & 7) * 8;
        const int q  = lane >> 3;                 // 0..7
        const unsigned short* base = xbh + c8;

        ushort4 ixr[9];
        #pragma unroll
        for (int it = 0; it < 9; ++it)
            ixr[it] = itab[wave * 72 + it * 8 + q];

        #pragma unroll
        for (int it = 0; it < 9; ++it) {
            const int e = wave * 72 + it * 8 + q;
            float4  wt  = wtab[e];
            int     dst = dsttab[e];
            ushort4 ix  = ixr[it];
            uint4 u00 = *(const uint4*)(base + ((size_t)ix.x << 6));
            uint4 u01 = *(const uint4*)(base + ((size_t)ix.y << 6));
            uint4 u10 = *(const uint4*)(base + ((size_t)ix.z << 6));
            uint4 u11 = *(const uint4*)(base + ((size_t)ix.w << 6));
            const unsigned int a00[4] = {u00.x, u00.y, u00.z, u00.w};
            const unsigned int a01[4] = {u01.x, u01.y, u01.z, u01.w};
            const unsigned int a10[4] = {u10.x, u10.y, u10.z, u10.w};
            const unsigned int a11[4] = {u11.x, u11.y, u11.z, u11.w};
            unsigned int pk[4];
            #pragma unroll
            for (int wd = 0; wd < 4; ++wd) {
                float slo = bf_lo(a00[wd]) * wt.x;
                slo = fmaf(bf_lo(a01[wd]), wt.y, slo);
                slo = fmaf(bf_lo(a10[wd]), wt.z, slo);
                slo = fmaf(bf_lo(a11[wd]), wt.w, slo);
                float shi = bf_hi(a00[wd]) * wt.x;
                shi = fmaf(bf_hi(a01[wd]), wt.y, shi);
                shi = fmaf(bf_hi(a10[wd]), wt.z, shi);
                shi = fmaf(bf_hi(a11[wd]), wt.w, shi);
                pk[wd] = pk2bf(slo, shi);
            }
            *(uint4*)&samp_s[dst + c8] = make_uint4(pk[0], pk[1], pk[2], pk[3]);
        }
    }
    __syncthreads();

    // ---- E: out[p][o] via MFMA; 1 bp load feeds 2 pixel halves
    {
        f32x4 acc0 = {0.f, 0.f, 0.f, 0.f};
        f32x4 acc1 = {0.f, 0.f, 0.f, 0.f};
        const unsigned short* bp = wB + ((size_t)(wave * 18) * 64 + lane) * 8;
        const int arow = (lane & 15) * ROWS + (lane >> 4) * 8;
        #pragma unroll
        for (int ks = 0; ks < 18; ++ks) {
            const int ro = arow + (ks >> 1) * KKS + (ks & 1) * 32;
            short8 av0 = *(const short8*)&samp_s[ro];
            short8 av1 = *(const short8*)&samp_s[ro + 16 * ROWS];
            short8 bv  = *(const short8*)bp;  bp += 512;
            acc0 = __builtin_amdgcn_mfma_f32_16x16x32_bf16(av0, bv, acc0, 0, 0, 0);
            acc1 = __builtin_amdgcn_mfma_f32_16x16x32_bf16(av1, bv, acc1, 0, 0, 0);
        }
        int o    = wave * 16 + (lane & 15);
        int prow = (lane >> 4) * 4;
        float* ob = out + (size_t)b * O_ * HW_ + (size_t)o * HW_ + ho * W_ + wo0;
        #pragma unroll
        for (int r = 0; r < 4; ++r) {
            ob[prow + r]      = acc0[r];
            ob[16 + prow + r] = acc1[r];
        }
    }
}

// ---------------- fallback: monolithic kernel (fp32 x_hwc) ----------------
__global__ __launch_bounds__(BDIM, 3) void dcn_mono(
    const float* __restrict__ xh,
    const float* __restrict__ b_off,
    const float* __restrict__ b_mod,
    const unsigned short* __restrict__ wB,
    const unsigned short* __restrict__ wO,
    float* __restrict__ out)
{
    __shared__ __align__(16) unsigned short samp_s[TP * ROWS];
    __shared__ __align__(16) float4 wtab[NE];
    __shared__ ushort4        itab[NE];
    __shared__ unsigned short dsttab[NE];

    float* offs = (float*)(samp_s + 8192);
    float* msk  = offs + TP * 18;

    const int t    = threadIdx.x;
    const int wave = t >> 6;
    const int lane = t & 63;
    const int blk  = ((blockIdx.x & 7) << 8) | (blockIdx.x >> 3);
    const int wo0  = (blk & 3) * TP;
    const int ho   = (blk >> 2) & 127;
    const int b    = blk >> 9;

    const float* xb = xh + (size_t)b * HW_ * C_;

    for (int u = t; u < 102 * 16; u += BDIM) {
        int row = u >> 4;
        int c4  = (u & 15) * 4;
        int ry  = row / XCOLS;
        int col = row - ry * XCOLS;
        int gy  = ho - 1 + ry;
        int gx  = wo0 - 1 + col;
        float4 v = make_float4(0.f, 0.f, 0.f, 0.f);
        if (gy >= 0 && gy < H_ && gx >= 0 && gx < W_)
            v = *(const float4*)&xb[(size_t)(gy * W_ + gx) * C_ + c4];
        *(uint2*)&samp_s[row * XTP + c4] = make_uint2(pk2bf(v.x, v.y), pk2bf(v.z, v.w));
    }
    __syncthreads();

    if (wave < 2) {
        f32x4 acc0 = {0.f, 0.f, 0.f, 0.f};
        f32x4 acc1 = {0.f, 0.f, 0.f, 0.f};
        const unsigned short* bp = wO + ((size_t)(wave * 18) * 64 + lane) * 8;
        const unsigned short* ap = samp_s + (lane & 15) * XTP + (lane >> 4) * 8;
        #pragma unroll
        for (int ks = 0; ks < 18; ++ks) {
            const int kk = ks >> 1, ky = kk / 3, kx = kk - ky * 3;
            const int ro = (ky * XCOLS + kx) * XTP + (ks & 1) * 32;
            short8 av0 = *(const short8*)&ap[ro];
            short8 av1 = *(const short8*)&ap[ro + 16 * XTP];
            short8 bv  = *(const short8*)bp;  bp += 512;
            acc0 = __builtin_amdgcn_mfma_f32_16x16x32_bf16(av0, bv, acc0, 0, 0, 0);
            acc1 = __builtin_amdgcn_mfma_f32_16x16x32_bf16(av1, bv, acc1, 0, 0, 0);
        }
        int oc   = wave * 16 + (lane & 15);
        int prow = (lane >> 4) * 4;
        if (oc < 18) {
            float bias = b_off[oc];
            #pragma unroll
            for (int r = 0; r < 4; ++r) {
                offs[(prow + r) * 18 + oc]      = acc0[r] + bias;
                offs[(prow + 16 + r) * 18 + oc] = acc1[r] + bias;
            }
        } else if (oc < 27) {
            int mc = oc - 18;
            float bias = b_mod[mc];
            #pragma unroll
            for (int r = 0; r < 4; ++r) {
                msk[(prow + r) * KK_ + mc]      = 2.f / (1.f + expf(-(acc0[r] + bias)));
                msk[(prow + 16 + r) * KK_ + mc] = 2.f / (1.f + expf(-(acc1[r] + bias)));
            }
        }
    }
    __syncthreads();

    for (int e = t; e < NE; e += BDIM) {
        int p  = e / 9;
        int kk = e - p * 9;
        int ky = kk / 3, kx = kk - ky * 3;
        float dy = offs[p * 18 + 2 * kk];
        float dx = offs[p * 18 + 2 * kk + 1];
        float py = dy + (float)(ho - 1 + ky);
        float px = dx + (float)(wo0 + p - 1 + kx);
        float y0f = floorf(py), x0f = floorf(px);
        float wy = py - y0f,    wx = px - x0f;
        int y0 = (int)y0f, x0 = (int)x0f;
        int y1 = y0 + 1,   x1 = x0 + 1;
        float m = msk[p * KK_ + kk];
        float vy0 = (y0 >= 0 && y0 < H_) ? 1.f : 0.f;
        float vy1 = (y1 >= 0 && y1 < H_) ? 1.f : 0.f;
        float vx0 = (x0 >= 0 && x0 < W_) ? 1.f : 0.f;
        float vx1 = (x1 >= 0 && x1 < W_) ? 1.f : 0.f;
        float4 wt;
        wt.x = (1.f - wy) * (1.f - wx) * m * vy0 * vx0;
        wt.y = (1.f - wy) * wx * m * vy0 * vx1;
        wt.z = wy * (1.f - wx) * m * vy1 * vx0;
        wt.w = wy * wx * m * vy1 * vx1;
        int yc0 = min(max(y0, 0), H_ - 1), yc1 = min(max(y1, 0), H_ - 1);
        int xc0 = min(max(x0, 0), W_ - 1), xc1 = min(max(x1, 0), W_ - 1);
        wtab[e] = wt;
        itab[e] = make_ushort4((unsigned short)(yc0 * W_ + xc0),
                               (unsigned short)(yc0 * W_ + xc1),
                               (unsigned short)(yc1 * W_ + xc0),
                               (unsigned short)(yc1 * W_ + xc1));
        dsttab[e] = (unsigned short)(p * ROWS + kk * KKS);
    }
    __syncthreads();

    {
        const int c4 = (lane & 15) * 4;
        const int q  = lane >> 4;
        const float* base = xb + c4;

        ushort4 ixr[18];
        #pragma unroll
        for (int it = 0; it < 18; ++it)
            ixr[it] = itab[wave * 72 + it * 4 + q];

        #define ISSUE(itv, d00, d01, d10, d11)                       \
            { ushort4 ix_ = ixr[itv];                                \
              d00 = *(const float4*)(base + ((size_t)ix_.x << 6));   \
              d01 = *(const float4*)(base + ((size_t)ix_.y << 6));   \
              d10 = *(const float4*)(base + ((size_t)ix_.z << 6));   \
              d11 = *(const float4*)(base + ((size_t)ix_.w << 6)); }

        float4 p00, p01, p10, p11;
        ISSUE(0, p00, p01, p10, p11);
        #pragma unroll
        for (int it = 0; it < 18; ++it) {
            float4 n00, n01, n10, n11;
            if (it < 17) ISSUE(it + 1, n00, n01, n10, n11);
            const int e = wave * 72 + it * 4 + q;
            float4 wt  = wtab[e];
            int    dst = dsttab[e];
            float s0 = p00.x * wt.x;
            s0 = fmaf(p01.x, wt.y, s0); s0 = fmaf(p10.x, wt.z, s0); s0 = fmaf(p11.x, wt.w, s0);
            float s1 = p00.y * wt.x;
            s1 = fmaf(p01.y, wt.y, s1); s1 = fmaf(p10.y, wt.z, s1); s1 = fmaf(p11.y, wt.w, s1);
            float s2 = p00.z * wt.x;
            s2 = fmaf(p01.z, wt.y, s2); s2 = fmaf(p10.z, wt.z, s2); s2 = fmaf(p11.z, wt.w, s2);
            float s3 = p00.w * wt.x;
            s3 = fmaf(p01.w, wt.y, s3); s3 = fmaf(p10.w, wt.z, s3); s3 = fmaf(p11.w, wt.w, s3);
            *(uint2*)&samp_s[dst + c4] = make_uint2(pk2bf(s0, s1), pk2bf(s2, s3));
            if (it < 17) { p00 = n00; p01 = n01; p10 = n10; p11 = n11; }
        }
        #undef ISSUE
    }
    __syncthreads();

    {
        f32x4 acc0 = {0.f, 0.f, 0.f, 0.f};
        f32x4 acc1 = {0.f, 0.f, 0.f, 0.f};
        const unsigned short* bp = wB + ((size_t)(wave * 18) * 64 + lane) * 8;
        const int arow = (lane & 15) * ROWS + (lane >> 4) * 8;
        #pragma unroll
        for (int ks = 0; ks < 18; ++ks) {
            const int ro = arow + (ks >> 1) * KKS + (ks & 1) * 32;
            short8 av0 = *(const short8*)&samp_s[ro];
            short8 av1 = *(const short8*)&samp_s[ro + 16 * ROWS];
            short8 bv  = *(const short8*)bp;  bp += 512;
            acc0 = __builtin_amdgcn_mfma_f32_16x16x32_bf16(av0, bv, acc0, 0, 0, 0);
            acc1 = __builtin_amdgcn_mfma_f32_16x16x32_bf16(av1, bv, acc1, 0, 0, 0);
        }
        int o    = wave * 16 + (lane & 15);
        int prow = (lane >> 4) * 4;
        float* ob = out + (size_t)b * O_ * HW_ + (size_t)o * HW_ + ho * W_ + wo0;
        #pragma unroll
        for (int r = 0; r < 4; ++r) {
            ob[prow + r]      = acc0[r];
            ob[16 + prow + r] = acc1[r];
        }
    }
}

extern "C" void kernel_launch(void* const* d_in, const int* in_sizes, int n_in,
                              void* d_out, int out_size, void* d_ws, size_t ws_size,
                              hipStream_t stream) {
    const float* x     = (const float*)d_in[0];
    const float* w_off = (const float*)d_in[1];
    const float* b_off = (const float*)d_in[2];
    const float* w_mod = (const float*)d_in[3];
    const float* b_mod = (const float*)d_in[4];
    const float* w_reg = (const float*)d_in[5];
    float* out = (float*)d_out;

    unsigned short* wpack = (unsigned short*)d_ws;

    if (ws_size >= WS_NEED) {
        float4*  wtab_g = (float4*)((char*)d_ws + WTAB_OFF);
        ushort4* itab_g = (ushort4*)((char*)d_ws + ITAB_OFF);
        unsigned short* x_hbf = (unsigned short*)((char*)d_ws + XHBF_OFF);
        dcn_pre<<<4096 + 216, BDIM, 0, stream>>>(x, (float*)x_hbf /*unused*/, x_hbf, 0,
                                                 w_off, w_mod, w_reg, wpack);
        dcn_tabs<<<NBLK, BDIM, 0, stream>>>(x_hbf, b_off, b_mod,
                                            wpack + 36864, wtab_g, itab_g);
        dcn_gather<<<NBLK, BDIM, 0, stream>>>(x_hbf, wtab_g, itab_g, wpack, out);
    } else {
        float* x_hwc = (float*)((char*)d_ws + XHWC_OFF);
        dcn_pre<<<4096 + 216, BDIM, 0, stream>>>(x, x_hwc, (unsigned short*)x_hwc /*unused*/, 1,
                                                 w_off, w_mod, w_reg, wpack);
        dcn_mono<<<NBLK, BDIM, 0, stream>>>(x_hwc, b_off, b_mod,
                                            wpack, wpack + 36864, out);
    }
}